// Round 9
// baseline (22.236 us; speedup 1.0000x reference)
//
#include <hip/hip_runtime.h>
#include <cmath>

#define HDIM 128
typedef float f32x2 __attribute__((ext_vector_type(2)));

constexpr float EPSF = 1e-5f;
constexpr float K2L  = 2.8853900817779268f;   // 2*log2(e)
constexpr float INVK = 0.34657359027997264f;  // ln(2)/2
constexpr float L2E  = 1.4426950408889634f;   // log2(e)
constexpr float LN2  = 0.6931471805599453f;
constexpr float UXXS = -2.0f * INVK * INVK;   // restores -2*c^2 scale in epilogue

__device__ inline float fast_rcp(float x) { return __builtin_amdgcn_rcpf(x); }

__device__ inline float fast_exp2(float x) {
#if __has_builtin(__builtin_amdgcn_exp2f)
    return __builtin_amdgcn_exp2f(x);
#else
    float r; asm("v_exp_f32 %0, %1" : "=v"(r) : "v"(x)); return r;
#endif
}

__device__ inline float fast_log2(float x) {
#if __has_builtin(__builtin_amdgcn_logf)
    return __builtin_amdgcn_logf(x);
#else
    float r; asm("v_log_f32 %0, %1" : "=v"(r) : "v"(x)); return r;
#endif
}

__device__ inline f32x2 splat2(float v) { return (f32x2){v, v}; }

__device__ inline f32x2 pk_fma(f32x2 a, f32x2 b, f32x2 c) {
#if __has_builtin(__builtin_elementwise_fma)
    return __builtin_elementwise_fma(a, b, c);
#else
    f32x2 r; r.x = fmaf(a.x, b.x, c.x); r.y = fmaf(a.y, b.y, c.y); return r;
#endif
}

__device__ inline double wave_reduce(double v) {
    #pragma unroll
    for (int off = 32; off > 0; off >>= 1)
        v += __shfl_down(v, off, 64);
    return v;
}

// ut,ux carry K2L scale; uxxp = +sum(wd*th*c'^2) carries K2L^2; UXXS restores -2/K2L^2.
__device__ inline void point_epilogue(float u, float ut, float ux, float uxxp,
                                      float x, float tgt,
                                      double& mspe, double& cal, double& bfly)
{
    const float q  = fast_exp2(-fabsf(u) * L2E);           // e^{-|u|}
    const float rp = fast_rcp(1.f + q);
    const float s  = (u >= 0.f) ? rp : q * rp;             // sigmoid(u)
    const float w_log  = fmaxf(u, 0.f) + LN2 * fast_log2(1.f + q);
    const float w_tail = q * fmaf(-0.5f, q, 1.f);          // softplus(u), u << 0
    const float w  = (u < -9.f) ? w_tail : w_log;

    const float utt  = ut * INVK;
    const float uxt  = ux * INVK;
    const float uxxt = uxxp * UXXS;
    const float w_t  = s * utt;
    const float w_x  = s * uxt;
    const float w_xx = fmaf(s * (1.f - s), uxt * uxt, s * uxxt);

    const float pe = (w - tgt) * fast_rcp(tgt + EPSF);
    mspe += (double)pe * (double)pe;

    const float ctm = fmaxf(-w_t, 0.f);
    cal += (double)ctm * (double)ctm;

    const float invw = fast_rcp(w);
    const float a1 = fmaf(-0.5f * x * w_x, invw, 1.f);
    const float g  = fmaf(0.5f, w_xx,
                     fmaf(a1, a1, -0.25f * w_x * (invw + 0.25f)));
    const float btm = fmaxf(-g, 0.f);
    bfly += (double)btm * (double)btm;
}

// 4 points/thread (two f32x2 pairs): one ds_read_b128 serves 4 points,
// joint reciprocal across 4 points (1 v_rcp + 7 muls via prefix/suffix).
__global__ __launch_bounds__(256, 1) void surf_loss_main(
    const float* __restrict__ tt, const float* __restrict__ xx,
    const float* __restrict__ tg,
    const float* __restrict__ W1, const float* __restrict__ b1,
    const float* __restrict__ W2, const float* __restrict__ b2,
    double* __restrict__ partials, int N)
{
    __shared__ float4 cs[HDIM];   // (A', C', B', W2), A',C',B' pre-scaled by K2L
    __shared__ double sred[3][4];
    const int tid = threadIdx.x;
    for (int i = tid; i < HDIM; i += 256) {
        cs[i] = make_float4(W1[i] * K2L, W1[HDIM + i] * K2L, b1[i] * K2L, W2[i]);
    }
    __syncthreads();
    const float b2v = b2[0];

    double mspe = 0.0, cal = 0.0, bfly = 0.0;

    const int nquad = N >> 2;
    const float4* __restrict__ tt4 = (const float4*)tt;
    const float4* __restrict__ xx4 = (const float4*)xx;
    const float4* __restrict__ tg4 = (const float4*)tg;

    for (int q = blockIdx.x * 256 + tid; q < nquad; q += gridDim.x * 256) {
        const float4 t4 = tt4[q], x4 = xx4[q], g4 = tg4[q];
        const f32x2 tA = {t4.x, t4.y}, tB = {t4.z, t4.w};
        const f32x2 xA = {x4.x, x4.y}, xB = {x4.z, x4.w};
        f32x2 uA   = splat2(0.f), uB   = splat2(0.f);
        f32x2 utA  = splat2(0.f), utB  = splat2(0.f);
        f32x2 uxA  = splat2(0.f), uxB  = splat2(0.f);
        f32x2 uxxA = splat2(0.f), uxxB = splat2(0.f);
        #pragma unroll 4
        for (int i = 0; i < HDIM; ++i) {
            const float4 c = cs[i];       // one LDS broadcast read for 4 points
            const f32x2 cxx = splat2(c.x), cyy = splat2(c.y);
            const f32x2 czz = splat2(c.z), cww = splat2(c.w);
            const f32x2 zA = pk_fma(tA, cxx, pk_fma(xA, cyy, czz));  // 2z*log2(e)
            const f32x2 zB = pk_fma(tB, cxx, pk_fma(xB, cyy, czz));
            f32x2 eA, eB;
            eA.x = fast_exp2(zA.x); eA.y = fast_exp2(zA.y);          // e^{2z}
            eB.x = fast_exp2(zB.x); eB.y = fast_exp2(zB.y);
            const f32x2 epA = eA + splat2(1.f);
            const f32x2 epB = eB + splat2(1.f);
            // joint reciprocal across 4 points: 1 v_rcp + 7 v_mul
            const float s1 = epA.x * epA.y;
            const float s2 = epB.x * epB.y;
            const float R  = fast_rcp(s1 * s2);
            const float RA = R * s2;                  // = 1/s1
            const float RB = R * s1;                  // = 1/s2
            f32x2 rA, rB;
            rA.x = RA * epA.y;  rA.y = RA * epA.x;    // 1/(1+e^{2z})
            rB.x = RB * epB.y;  rB.y = RB * epB.x;
            const f32x2 thA = pk_fma(splat2(-2.f), rA, splat2(1.f)); // tanh(z)
            const f32x2 thB = pk_fma(splat2(-2.f), rB, splat2(1.f));
            const f32x2 dA  = pk_fma(-thA, thA, splat2(1.f));        // sech^2(z)
            const f32x2 dB  = pk_fma(-thB, thB, splat2(1.f));
            const f32x2 wdA = dA * cww;
            const f32x2 wdB = dB * cww;
            uA   = pk_fma(thA, cww, uA);
            uB   = pk_fma(thB, cww, uB);
            utA  = pk_fma(wdA, cxx, utA);
            utB  = pk_fma(wdB, cxx, utB);
            uxA  = pk_fma(wdA, cyy, uxA);
            uxB  = pk_fma(wdB, cyy, uxB);
            const f32x2 wtcA = (wdA * thA) * cyy;
            const f32x2 wtcB = (wdB * thB) * cyy;
            uxxA = pk_fma(wtcA, cyy, uxxA);                          // +sum wd*th*c'^2
            uxxB = pk_fma(wtcB, cyy, uxxB);
        }
        point_epilogue(uA.x + b2v, utA.x, uxA.x, uxxA.x, x4.x, g4.x, mspe, cal, bfly);
        point_epilogue(uA.y + b2v, utA.y, uxA.y, uxxA.y, x4.y, g4.y, mspe, cal, bfly);
        point_epilogue(uB.x + b2v, utB.x, uxB.x, uxxB.x, x4.z, g4.z, mspe, cal, bfly);
        point_epilogue(uB.y + b2v, utB.y, uxB.y, uxxB.y, x4.w, g4.w, mspe, cal, bfly);
    }

    // tail: up to 3 leftover points, scalar on block 0 / thread 0
    if (blockIdx.x == 0 && tid == 0) {
        for (int idx = (N >> 2) << 2; idx < N; ++idx) {
            const float t = tt[idx], x = xx[idx], tgt = tg[idx];
            float u = 0.f, ut = 0.f, ux = 0.f, uxx = 0.f;
            for (int i = 0; i < HDIM; ++i) {
                const float4 c = cs[i];
                const float zp = fmaf(t, c.x, fmaf(x, c.y, c.z));
                const float e  = fast_exp2(zp);
                const float r  = fast_rcp(e + 1.f);
                const float th = fmaf(-2.f, r, 1.f);
                const float d  = fmaf(-th, th, 1.f);
                const float wd = c.w * d;
                u   = fmaf(c.w, th, u);
                ut  = fmaf(wd, c.x, ut);
                ux  = fmaf(wd, c.y, ux);
                uxx = fmaf(wd * th * c.y, c.y, uxx);
            }
            point_epilogue(u + b2v, ut, ux, uxx, x, tgt, mspe, cal, bfly);
        }
    }

    double v0 = wave_reduce(mspe), v1 = wave_reduce(cal), v2 = wave_reduce(bfly);
    const int wid = tid >> 6, lane = tid & 63;
    if (lane == 0) { sred[0][wid] = v0; sred[1][wid] = v1; sred[2][wid] = v2; }
    __syncthreads();
    if (tid == 0) {
        double a = 0, b = 0, c = 0;
        #pragma unroll
        for (int wv = 0; wv < 4; ++wv) { a += sred[0][wv]; b += sred[1][wv]; c += sred[2][wv]; }
        partials[blockIdx.x * 3 + 0] = a;
        partials[blockIdx.x * 3 + 1] = b;
        partials[blockIdx.x * 3 + 2] = c;
    }
}

__global__ __launch_bounds__(256) void surf_loss_final(
    const double* __restrict__ partials, int nblocks, float* __restrict__ out, int N)
{
    const int tid = threadIdx.x;
    double a = 0, b = 0, c = 0;
    for (int i = tid; i < nblocks; i += 256) {
        a += partials[i * 3 + 0];
        b += partials[i * 3 + 1];
        c += partials[i * 3 + 2];
    }
    a = wave_reduce(a); b = wave_reduce(b); c = wave_reduce(c);
    __shared__ double sred[3][4];
    const int wid = tid >> 6, lane = tid & 63;
    if (lane == 0) { sred[0][wid] = a; sred[1][wid] = b; sred[2][wid] = c; }
    __syncthreads();
    if (tid == 0) {
        const double inv = 1.0 / (double)N;
        double s0 = 0, s1 = 0, s2 = 0;
        #pragma unroll
        for (int wv = 0; wv < 4; ++wv) { s0 += sred[0][wv]; s1 += sred[1][wv]; s2 += sred[2][wv]; }
        out[0] = (float)(s0 * inv);
        out[1] = (float)(s1 * inv);
        out[2] = (float)(s2 * inv);
    }
}

extern "C" void kernel_launch(void* const* d_in, const int* in_sizes, int n_in,
                              void* d_out, int out_size, void* d_ws, size_t ws_size,
                              hipStream_t stream) {
    const float* tt = (const float*)d_in[0];
    const float* xx = (const float*)d_in[1];
    const float* tg = (const float*)d_in[2];
    const float* W1 = (const float*)d_in[3];
    const float* b1 = (const float*)d_in[4];
    const float* W2 = (const float*)d_in[5];
    const float* b2 = (const float*)d_in[6];
    const int N = in_sizes[0];

    const int nquad = N >> 2;
    int blocks = (nquad + 255) / 256;
    if (blocks < 1) blocks = 1;
    if (blocks > 1024) blocks = 1024;
    while ((size_t)blocks * 3 * sizeof(double) > ws_size && blocks > 1) blocks >>= 1;

    double* partials = (double*)d_ws;
    surf_loss_main<<<blocks, 256, 0, stream>>>(tt, xx, tg, W1, b1, W2, b2, partials, N);
    surf_loss_final<<<1, 256, 0, stream>>>(partials, blocks, (float*)d_out, N);
}

// Round 10
// 21.428 us; speedup vs baseline: 1.0377x; 1.0377x over previous
//
#include <hip/hip_runtime.h>
#include <cmath>

#define HDIM 128
typedef float f32x2 __attribute__((ext_vector_type(2)));

constexpr float EPSF = 1e-5f;
constexpr float K2L  = 2.8853900817779268f;   // 2*log2(e)
constexpr float INVK = 0.34657359027997264f;  // ln(2)/2
constexpr float L2E  = 1.4426950408889634f;   // log2(e)
constexpr float LN2  = 0.6931471805599453f;
constexpr float UXXS = -2.0f * INVK * INVK;   // restores -2*c^2 scale in epilogue

__device__ inline float fast_rcp(float x) { return __builtin_amdgcn_rcpf(x); }

__device__ inline float fast_exp2(float x) {
#if __has_builtin(__builtin_amdgcn_exp2f)
    return __builtin_amdgcn_exp2f(x);
#else
    float r; asm("v_exp_f32 %0, %1" : "=v"(r) : "v"(x)); return r;
#endif
}

__device__ inline float fast_log2(float x) {
#if __has_builtin(__builtin_amdgcn_logf)
    return __builtin_amdgcn_logf(x);
#else
    float r; asm("v_log_f32 %0, %1" : "=v"(r) : "v"(x)); return r;
#endif
}

__device__ inline f32x2 splat2(float v) { return (f32x2){v, v}; }

__device__ inline f32x2 pk_fma(f32x2 a, f32x2 b, f32x2 c) {
#if __has_builtin(__builtin_elementwise_fma)
    return __builtin_elementwise_fma(a, b, c);
#else
    f32x2 r; r.x = fmaf(a.x, b.x, c.x); r.y = fmaf(a.y, b.y, c.y); return r;
#endif
}

__device__ inline double wave_reduce(double v) {
    #pragma unroll
    for (int off = 32; off > 0; off >>= 1)
        v += __shfl_down(v, off, 64);
    return v;
}

// ut,ux carry K2L scale; uxxp = +sum(wd*th*c'^2) carries K2L^2; UXXS restores -2/K2L^2.
__device__ inline void point_epilogue(float u, float ut, float ux, float uxxp,
                                      float x, float tgt,
                                      double& mspe, double& cal, double& bfly)
{
    const float q  = fast_exp2(-fabsf(u) * L2E);           // e^{-|u|}
    const float rp = fast_rcp(1.f + q);
    const float s  = (u >= 0.f) ? rp : q * rp;             // sigmoid(u)
    const float w_log  = fmaxf(u, 0.f) + LN2 * fast_log2(1.f + q);
    const float w_tail = q * fmaf(-0.5f, q, 1.f);          // softplus(u), u << 0
    const float w  = (u < -9.f) ? w_tail : w_log;

    const float utt  = ut * INVK;
    const float uxt  = ux * INVK;
    const float uxxt = uxxp * UXXS;
    const float w_t  = s * utt;
    const float w_x  = s * uxt;
    const float w_xx = fmaf(s * (1.f - s), uxt * uxt, s * uxxt);

    const float pe = (w - tgt) * fast_rcp(tgt + EPSF);
    mspe += (double)pe * (double)pe;

    const float ctm = fmaxf(-w_t, 0.f);
    cal += (double)ctm * (double)ctm;

    const float invw = fast_rcp(w);
    const float a1 = fmaf(-0.5f * x * w_x, invw, 1.f);
    const float g  = fmaf(0.5f, w_xx,
                     fmaf(a1, a1, -0.25f * w_x * (invw + 0.25f)));
    const float btm = fmaxf(-g, 0.f);
    bfly += (double)btm * (double)btm;
}

// R8 body (2 pt/thread, joint-rcp) + distance-2 LDS prefetch of the weight vector.
__global__ __launch_bounds__(256, 2) void surf_loss_main(
    const float* __restrict__ tt, const float* __restrict__ xx,
    const float* __restrict__ tg,
    const float* __restrict__ W1, const float* __restrict__ b1,
    const float* __restrict__ W2, const float* __restrict__ b2,
    double* __restrict__ partials, int N)
{
    __shared__ float4 cs[HDIM];   // (A', C', B', W2), A',C',B' pre-scaled by K2L
    __shared__ double sred[3][4];
    const int tid = threadIdx.x;
    for (int i = tid; i < HDIM; i += 256) {
        cs[i] = make_float4(W1[i] * K2L, W1[HDIM + i] * K2L, b1[i] * K2L, W2[i]);
    }
    __syncthreads();
    const float b2v = b2[0];

    double mspe = 0.0, cal = 0.0, bfly = 0.0;

    const int npair = N >> 1;
    const f32x2* __restrict__ tt2 = (const f32x2*)tt;
    const f32x2* __restrict__ xx2 = (const f32x2*)xx;
    const f32x2* __restrict__ tg2 = (const f32x2*)tg;

    for (int p = blockIdx.x * 256 + tid; p < npair; p += gridDim.x * 256) {
        const f32x2 t2 = tt2[p], x2 = xx2[p], g2 = tg2[p];
        f32x2 u2   = splat2(0.f);
        f32x2 ut2  = splat2(0.f);
        f32x2 ux2  = splat2(0.f);
        f32x2 uxx2 = splat2(0.f);
        // software pipeline: weight vectors rotate through registers,
        // ds_read for i+2 issues before compute of i consumes c0.
        float4 c0 = cs[0], c1 = cs[1];
        #pragma unroll 4
        for (int i = 0; i < HDIM; ++i) {
            const float4 cn = cs[(i + 2) & (HDIM - 1)];   // prefetch distance 2
            const float4 c  = c0;
            const f32x2 z  = pk_fma(t2, splat2(c.x),
                              pk_fma(x2, splat2(c.y), splat2(c.z)));  // 2z*log2(e)
            f32x2 e;  e.x = fast_exp2(z.x); e.y = fast_exp2(z.y);     // e^{2z}
            const f32x2 ep = e + splat2(1.f);
            const float R  = fast_rcp(ep.x * ep.y);    // joint reciprocal: 1 trans
            f32x2 r;  r.x = R * ep.y;  r.y = R * ep.x; // 1/(1+e^{2z})
            const f32x2 th = pk_fma(splat2(-2.f), r, splat2(1.f));    // tanh(z)
            const f32x2 d  = pk_fma(-th, th, splat2(1.f));            // sech^2(z)
            const f32x2 wd = d * splat2(c.w);
            u2   = pk_fma(th, splat2(c.w), u2);
            ut2  = pk_fma(wd, splat2(c.x), ut2);
            ux2  = pk_fma(wd, splat2(c.y), ux2);
            const f32x2 wt  = wd * th;
            const f32x2 wtc = wt * splat2(c.y);
            uxx2 = pk_fma(wtc, splat2(c.y), uxx2);                    // +sum wd*th*c'^2
            c0 = c1; c1 = cn;
        }
        point_epilogue(u2.x + b2v, ut2.x, ux2.x, uxx2.x, x2.x, g2.x, mspe, cal, bfly);
        point_epilogue(u2.y + b2v, ut2.y, ux2.y, uxx2.y, x2.y, g2.y, mspe, cal, bfly);
    }

    // odd-N tail: one scalar point
    if ((N & 1) && blockIdx.x == 0 && tid == 0) {
        const int idx = N - 1;
        const float t = tt[idx], x = xx[idx], tgt = tg[idx];
        float u = 0.f, ut = 0.f, ux = 0.f, uxx = 0.f;
        for (int i = 0; i < HDIM; ++i) {
            const float4 c = cs[i];
            const float zp = fmaf(t, c.x, fmaf(x, c.y, c.z));
            const float e  = fast_exp2(zp);
            const float r  = fast_rcp(e + 1.f);
            const float th = fmaf(-2.f, r, 1.f);
            const float d  = fmaf(-th, th, 1.f);
            const float wd = c.w * d;
            u   = fmaf(c.w, th, u);
            ut  = fmaf(wd, c.x, ut);
            ux  = fmaf(wd, c.y, ux);
            uxx = fmaf(wd * th * c.y, c.y, uxx);
        }
        point_epilogue(u + b2v, ut, ux, uxx, x, tgt, mspe, cal, bfly);
    }

    double v0 = wave_reduce(mspe), v1 = wave_reduce(cal), v2 = wave_reduce(bfly);
    const int wid = tid >> 6, lane = tid & 63;
    if (lane == 0) { sred[0][wid] = v0; sred[1][wid] = v1; sred[2][wid] = v2; }
    __syncthreads();
    if (tid == 0) {
        double a = 0, b = 0, c = 0;
        #pragma unroll
        for (int wv = 0; wv < 4; ++wv) { a += sred[0][wv]; b += sred[1][wv]; c += sred[2][wv]; }
        partials[blockIdx.x * 3 + 0] = a;
        partials[blockIdx.x * 3 + 1] = b;
        partials[blockIdx.x * 3 + 2] = c;
    }
}

__global__ __launch_bounds__(256) void surf_loss_final(
    const double* __restrict__ partials, int nblocks, float* __restrict__ out, int N)
{
    const int tid = threadIdx.x;
    double a = 0, b = 0, c = 0;
    for (int i = tid; i < nblocks; i += 256) {
        a += partials[i * 3 + 0];
        b += partials[i * 3 + 1];
        c += partials[i * 3 + 2];
    }
    a = wave_reduce(a); b = wave_reduce(b); c = wave_reduce(c);
    __shared__ double sred[3][4];
    const int wid = tid >> 6, lane = tid & 63;
    if (lane == 0) { sred[0][wid] = a; sred[1][wid] = b; sred[2][wid] = c; }
    __syncthreads();
    if (tid == 0) {
        const double inv = 1.0 / (double)N;
        double s0 = 0, s1 = 0, s2 = 0;
        #pragma unroll
        for (int wv = 0; wv < 4; ++wv) { s0 += sred[0][wv]; s1 += sred[1][wv]; s2 += sred[2][wv]; }
        out[0] = (float)(s0 * inv);
        out[1] = (float)(s1 * inv);
        out[2] = (float)(s2 * inv);
    }
}

extern "C" void kernel_launch(void* const* d_in, const int* in_sizes, int n_in,
                              void* d_out, int out_size, void* d_ws, size_t ws_size,
                              hipStream_t stream) {
    const float* tt = (const float*)d_in[0];
    const float* xx = (const float*)d_in[1];
    const float* tg = (const float*)d_in[2];
    const float* W1 = (const float*)d_in[3];
    const float* b1 = (const float*)d_in[4];
    const float* W2 = (const float*)d_in[5];
    const float* b2 = (const float*)d_in[6];
    const int N = in_sizes[0];

    const int npair = N >> 1;
    int blocks = (npair + 255) / 256;
    if (blocks < 1) blocks = 1;
    if (blocks > 1024) blocks = 1024;
    while ((size_t)blocks * 3 * sizeof(double) > ws_size && blocks > 1) blocks >>= 1;

    double* partials = (double*)d_ws;
    surf_loss_main<<<blocks, 256, 0, stream>>>(tt, xx, tg, W1, b1, W2, b2, partials, N);
    surf_loss_final<<<1, 256, 0, stream>>>(partials, blocks, (float*)d_out, N);
}

// Round 11
// 20.254 us; speedup vs baseline: 1.0978x; 1.0580x over previous
//
#include <hip/hip_runtime.h>
#include <cmath>

#define HDIM 128
typedef float f32x2 __attribute__((ext_vector_type(2)));

constexpr float EPSF = 1e-5f;
constexpr float K2L  = 2.8853900817779268f;   // 2*log2(e)
constexpr float INVK = 0.34657359027997264f;  // ln(2)/2
constexpr float L2E  = 1.4426950408889634f;   // log2(e)
constexpr float LN2  = 0.6931471805599453f;
constexpr float UXXS = -2.0f * INVK * INVK;   // restores -2*c^2 scale in epilogue

__device__ inline float fast_rcp(float x) { return __builtin_amdgcn_rcpf(x); }

__device__ inline float fast_exp2(float x) {
#if __has_builtin(__builtin_amdgcn_exp2f)
    return __builtin_amdgcn_exp2f(x);
#else
    float r; asm("v_exp_f32 %0, %1" : "=v"(r) : "v"(x)); return r;
#endif
}

__device__ inline float fast_log2(float x) {
#if __has_builtin(__builtin_amdgcn_logf)
    return __builtin_amdgcn_logf(x);
#else
    float r; asm("v_log_f32 %0, %1" : "=v"(r) : "v"(x)); return r;
#endif
}

__device__ inline f32x2 splat2(float v) { return (f32x2){v, v}; }

__device__ inline f32x2 pk_fma(f32x2 a, f32x2 b, f32x2 c) {
#if __has_builtin(__builtin_elementwise_fma)
    return __builtin_elementwise_fma(a, b, c);
#else
    f32x2 r; r.x = fmaf(a.x, b.x, c.x); r.y = fmaf(a.y, b.y, c.y); return r;
#endif
}

__device__ inline double wave_reduce(double v) {
    #pragma unroll
    for (int off = 32; off > 0; off >>= 1)
        v += __shfl_down(v, off, 64);
    return v;
}

// ut,ux carry K2L scale; uxxp = +sum(wd*th*c'^2) carries K2L^2; UXXS restores -2/K2L^2.
__device__ inline void point_epilogue(float u, float ut, float ux, float uxxp,
                                      float x, float tgt,
                                      double& mspe, double& cal, double& bfly)
{
    const float q  = fast_exp2(-fabsf(u) * L2E);           // e^{-|u|}
    const float rp = fast_rcp(1.f + q);
    const float s  = (u >= 0.f) ? rp : q * rp;             // sigmoid(u)
    const float w_log  = fmaxf(u, 0.f) + LN2 * fast_log2(1.f + q);
    const float w_tail = q * fmaf(-0.5f, q, 1.f);          // softplus(u), u << 0
    const float w  = (u < -9.f) ? w_tail : w_log;

    const float utt  = ut * INVK;
    const float uxt  = ux * INVK;
    const float uxxt = uxxp * UXXS;
    const float w_t  = s * utt;
    const float w_x  = s * uxt;
    const float w_xx = fmaf(s * (1.f - s), uxt * uxt, s * uxxt);

    const float pe = (w - tgt) * fast_rcp(tgt + EPSF);
    mspe += (double)pe * (double)pe;

    const float ctm = fmaxf(-w_t, 0.f);
    cal += (double)ctm * (double)ctm;

    const float invw = fast_rcp(w);
    const float a1 = fmaf(-0.5f * x * w_x, invw, 1.f);
    const float g  = fmaf(0.5f, w_xx,
                     fmaf(a1, a1, -0.25f * w_x * (invw + 0.25f)));
    const float btm = fmaxf(-g, 0.f);
    bfly += (double)btm * (double)btm;
}

// Best-measured configuration (R8, 20.28 us): two-kernel topology, 2 points/thread
// pair-packed, single float4 LDS broadcast per unit, joint reciprocal (1 trans).
__global__ __launch_bounds__(256, 2) void surf_loss_main(
    const float* __restrict__ tt, const float* __restrict__ xx,
    const float* __restrict__ tg,
    const float* __restrict__ W1, const float* __restrict__ b1,
    const float* __restrict__ W2, const float* __restrict__ b2,
    double* __restrict__ partials, int N)
{
    __shared__ float4 cs[HDIM];   // (A', C', B', W2), A',C',B' pre-scaled by K2L
    __shared__ double sred[3][4];
    const int tid = threadIdx.x;
    for (int i = tid; i < HDIM; i += 256) {
        cs[i] = make_float4(W1[i] * K2L, W1[HDIM + i] * K2L, b1[i] * K2L, W2[i]);
    }
    __syncthreads();
    const float b2v = b2[0];

    double mspe = 0.0, cal = 0.0, bfly = 0.0;

    const int npair = N >> 1;
    const f32x2* __restrict__ tt2 = (const f32x2*)tt;
    const f32x2* __restrict__ xx2 = (const f32x2*)xx;
    const f32x2* __restrict__ tg2 = (const f32x2*)tg;

    for (int p = blockIdx.x * 256 + tid; p < npair; p += gridDim.x * 256) {
        const f32x2 t2 = tt2[p], x2 = xx2[p], g2 = tg2[p];
        f32x2 u2   = splat2(0.f);
        f32x2 ut2  = splat2(0.f);
        f32x2 ux2  = splat2(0.f);
        f32x2 uxx2 = splat2(0.f);
        #pragma unroll 8
        for (int i = 0; i < HDIM; ++i) {
            const float4 c = cs[i];       // uniform index -> LDS broadcast
            const f32x2 z  = pk_fma(t2, splat2(c.x),
                              pk_fma(x2, splat2(c.y), splat2(c.z)));  // 2z*log2(e)
            f32x2 e;  e.x = fast_exp2(z.x); e.y = fast_exp2(z.y);     // e^{2z}
            const f32x2 ep = e + splat2(1.f);
            const float R  = fast_rcp(ep.x * ep.y);    // joint reciprocal: 1 trans
            f32x2 r;  r.x = R * ep.y;  r.y = R * ep.x; // 1/(1+e^{2z})
            const f32x2 th = pk_fma(splat2(-2.f), r, splat2(1.f));    // tanh(z)
            const f32x2 d  = pk_fma(-th, th, splat2(1.f));            // sech^2(z)
            const f32x2 wd = d * splat2(c.w);
            u2   = pk_fma(th, splat2(c.w), u2);
            ut2  = pk_fma(wd, splat2(c.x), ut2);
            ux2  = pk_fma(wd, splat2(c.y), ux2);
            const f32x2 wt  = wd * th;
            const f32x2 wtc = wt * splat2(c.y);
            uxx2 = pk_fma(wtc, splat2(c.y), uxx2);                    // +sum wd*th*c'^2
        }
        point_epilogue(u2.x + b2v, ut2.x, ux2.x, uxx2.x, x2.x, g2.x, mspe, cal, bfly);
        point_epilogue(u2.y + b2v, ut2.y, ux2.y, uxx2.y, x2.y, g2.y, mspe, cal, bfly);
    }

    // odd-N tail: one scalar point
    if ((N & 1) && blockIdx.x == 0 && tid == 0) {
        const int idx = N - 1;
        const float t = tt[idx], x = xx[idx], tgt = tg[idx];
        float u = 0.f, ut = 0.f, ux = 0.f, uxx = 0.f;
        for (int i = 0; i < HDIM; ++i) {
            const float4 c = cs[i];
            const float zp = fmaf(t, c.x, fmaf(x, c.y, c.z));
            const float e  = fast_exp2(zp);
            const float r  = fast_rcp(e + 1.f);
            const float th = fmaf(-2.f, r, 1.f);
            const float d  = fmaf(-th, th, 1.f);
            const float wd = c.w * d;
            u   = fmaf(c.w, th, u);
            ut  = fmaf(wd, c.x, ut);
            ux  = fmaf(wd, c.y, ux);
            uxx = fmaf(wd * th * c.y, c.y, uxx);
        }
        point_epilogue(u + b2v, ut, ux, uxx, x, tgt, mspe, cal, bfly);
    }

    double v0 = wave_reduce(mspe), v1 = wave_reduce(cal), v2 = wave_reduce(bfly);
    const int wid = tid >> 6, lane = tid & 63;
    if (lane == 0) { sred[0][wid] = v0; sred[1][wid] = v1; sred[2][wid] = v2; }
    __syncthreads();
    if (tid == 0) {
        double a = 0, b = 0, c = 0;
        #pragma unroll
        for (int wv = 0; wv < 4; ++wv) { a += sred[0][wv]; b += sred[1][wv]; c += sred[2][wv]; }
        partials[blockIdx.x * 3 + 0] = a;
        partials[blockIdx.x * 3 + 1] = b;
        partials[blockIdx.x * 3 + 2] = c;
    }
}

__global__ __launch_bounds__(256) void surf_loss_final(
    const double* __restrict__ partials, int nblocks, float* __restrict__ out, int N)
{
    const int tid = threadIdx.x;
    double a = 0, b = 0, c = 0;
    for (int i = tid; i < nblocks; i += 256) {
        a += partials[i * 3 + 0];
        b += partials[i * 3 + 1];
        c += partials[i * 3 + 2];
    }
    a = wave_reduce(a); b = wave_reduce(b); c = wave_reduce(c);
    __shared__ double sred[3][4];
    const int wid = tid >> 6, lane = tid & 63;
    if (lane == 0) { sred[0][wid] = a; sred[1][wid] = b; sred[2][wid] = c; }
    __syncthreads();
    if (tid == 0) {
        const double inv = 1.0 / (double)N;
        double s0 = 0, s1 = 0, s2 = 0;
        #pragma unroll
        for (int wv = 0; wv < 4; ++wv) { s0 += sred[0][wv]; s1 += sred[1][wv]; s2 += sred[2][wv]; }
        out[0] = (float)(s0 * inv);
        out[1] = (float)(s1 * inv);
        out[2] = (float)(s2 * inv);
    }
}

extern "C" void kernel_launch(void* const* d_in, const int* in_sizes, int n_in,
                              void* d_out, int out_size, void* d_ws, size_t ws_size,
                              hipStream_t stream) {
    const float* tt = (const float*)d_in[0];
    const float* xx = (const float*)d_in[1];
    const float* tg = (const float*)d_in[2];
    const float* W1 = (const float*)d_in[3];
    const float* b1 = (const float*)d_in[4];
    const float* W2 = (const float*)d_in[5];
    const float* b2 = (const float*)d_in[6];
    const int N = in_sizes[0];

    const int npair = N >> 1;
    int blocks = (npair + 255) / 256;
    if (blocks < 1) blocks = 1;
    if (blocks > 1024) blocks = 1024;
    while ((size_t)blocks * 3 * sizeof(double) > ws_size && blocks > 1) blocks >>= 1;

    double* partials = (double*)d_ws;
    surf_loss_main<<<blocks, 256, 0, stream>>>(tt, xx, tg, W1, b1, W2, b2, partials, N);
    surf_loss_final<<<1, 256, 0, stream>>>(partials, blocks, (float*)d_out, N);
}